// Round 19
// baseline (97.033 us; speedup 1.0000x reference)
//
#include <hip/hip_runtime.h>

#define N_TOK 2048
#define IN_FEAT 2048
#define NNZB 1228
#define XN8 ((N_TOK * IN_FEAT) / 8)   // x elements / 8
#define WN8 ((NNZB * 1024) / 8)       // w elements / 8

typedef __attribute__((ext_vector_type(8))) short short8;
typedef __attribute__((ext_vector_type(4))) float floatx4;

__device__ __forceinline__ short f2bf(float f) {
  unsigned u = __builtin_bit_cast(unsigned, f);
  u += 0x7FFFu + ((u >> 16) & 1u);   // round-to-nearest-even
  return (short)(u >> 16);
}

__device__ __forceinline__ short8 cvt8(const float4 a, const float4 b) {
  short8 r;
  r[0] = f2bf(a.x); r[1] = f2bf(a.y); r[2] = f2bf(a.z); r[3] = f2bf(a.w);
  r[4] = f2bf(b.x); r[5] = f2bf(b.y); r[6] = f2bf(b.z); r[7] = f2bf(b.w);
  return r;
}

// f32 -> bf16 staging, xb COLUMN-BLOCK-MAJOR: xb[(ib*2048 + tok)*32 + col].
// (R18 win: A-fragment = 1KB contiguous, kills the 4KB-stride L1 set aliasing.)
__global__ __launch_bounds__(256) void cvt_kernel(
    const float* __restrict__ x, const float* __restrict__ w,
    const int* __restrict__ oi,
    short8* __restrict__ xb, short8* __restrict__ wb, int* __restrict__ offs) {
  const int tid = blockIdx.x * 256 + threadIdx.x;
  if (blockIdx.x == 0 && threadIdx.x < 65) {
    const int target = threadIdx.x;
    int lo = 0, hi = NNZB;
    while (lo < hi) { int m = (lo + hi) >> 1; if (oi[m] < target) lo = m + 1; else hi = m; }
    offs[threadIdx.x] = lo;
  }
  if (tid < XN8) {
    const int cg  = tid & 3;
    const int tok = (tid >> 2) & (N_TOK - 1);
    const int ib  = tid >> 13;
    const float4* p = (const float4*)x + ((size_t)tok * 512 + ib * 8 + cg * 2);
    xb[tid] = cvt8(p[0], p[1]);
  } else if (tid < XN8 + WN8) {
    const int t = tid - XN8;
    const float4* p = (const float4*)w + (size_t)t * 2;
    wb[t] = cvt8(p[0], p[1]);
  }
}

// R18 layout + R17 2-deep software pipeline (named A/B register sets).
// R18 post-mortem: layout fix -9.3us (L1 set conflict was real); residual
// k-loop ~2-3x above L1-BW floor => un-hidden L2 latency, now attackable by
// prefetch since loads are no longer set-serialized.
template <int USE_WS>
__global__ __launch_bounds__(256, 4) void bsl_main(
    const short8* __restrict__ xb, const short8* __restrict__ wb,
    const int* __restrict__ offs,
    const float* __restrict__ x, const float* __restrict__ w,
    const int* __restrict__ oi, const int* __restrict__ ii,
    float* __restrict__ y) {
  const int ob   = blockIdx.x >> 5;
  const int tile = blockIdx.x & 31;
  const int lane = threadIdx.x & 63;
  const int wv   = __builtin_amdgcn_readfirstlane(threadIdx.x >> 6);
  const int row16 = lane & 15;
  const int kgrp  = lane >> 4;   // 0..3

  __shared__ float red[2][64 * 32];

  int e0, e1;
  if (USE_WS) {
    e0 = offs[ob];
    e1 = offs[ob + 1];
  } else {
    int lo = 0, hi = NNZB;
    while (lo < hi) { int m = (lo + hi) >> 1; if (oi[m] < ob) lo = m + 1; else hi = m; }
    e0 = lo;
    hi = NNZB;
    while (lo < hi) { int m = (lo + hi) >> 1; if (oi[m] < ob + 1) lo = m + 1; else hi = m; }
    e1 = lo;
  }
  const int cnt = e1 - e0;

  // preload up to 64 block indices into the wave's lanes (one load total)
  const int safek = (lane < cnt) ? (e0 + lane) : 0;
  const int iiv = ii[safek];

  const int ks = (cnt * wv) >> 2;
  const int ke = (cnt * (wv + 1)) >> 2;
  const int len = ke - ks;

  const int tokBase = tile * 64;

  floatx4 acc[4][2] = {};

  if (USE_WS) {
    if (len > 0) {
      const short8* xbase = xb + (size_t)(tokBase + row16) * 4 + kgrp;

      short8 b0A, b1A, a0A, a1A, a2A, a3A;
      short8 b0B, b1B, a0B, a1B, a2B, a3B;

#define LD(j_, b0_, b1_, a0_, a1_, a2_, a3_)                                   \
  {                                                                            \
    const int j__ = (j_);                                                      \
    const int k__ = e0 + j__;                                                  \
    const int ib__ = (j__ < 64) ? __builtin_amdgcn_readlane(iiv, j__)          \
                                : ii[k__];                                     \
    const short8* wp__ = wb + (size_t)k__ * 128 + row16 * 4 + kgrp;            \
    b0_ = wp__[0];                                                             \
    b1_ = wp__[64];                                                            \
    const short8* xp__ = xbase + (size_t)ib__ * 8192;                          \
    a0_ = xp__[0];                                                             \
    a1_ = xp__[64];                                                            \
    a2_ = xp__[128];                                                           \
    a3_ = xp__[192];                                                           \
  }

#define FMA(b0_, b1_, a0_, a1_, a2_, a3_)                                      \
  {                                                                            \
    acc[0][0] = __builtin_amdgcn_mfma_f32_16x16x32_bf16(a0_, b0_, acc[0][0], 0, 0, 0); \
    acc[0][1] = __builtin_amdgcn_mfma_f32_16x16x32_bf16(a0_, b1_, acc[0][1], 0, 0, 0); \
    acc[1][0] = __builtin_amdgcn_mfma_f32_16x16x32_bf16(a1_, b0_, acc[1][0], 0, 0, 0); \
    acc[1][1] = __builtin_amdgcn_mfma_f32_16x16x32_bf16(a1_, b1_, acc[1][1], 0, 0, 0); \
    acc[2][0] = __builtin_amdgcn_mfma_f32_16x16x32_bf16(a2_, b0_, acc[2][0], 0, 0, 0); \
    acc[2][1] = __builtin_amdgcn_mfma_f32_16x16x32_bf16(a2_, b1_, acc[2][1], 0, 0, 0); \
    acc[3][0] = __builtin_amdgcn_mfma_f32_16x16x32_bf16(a3_, b0_, acc[3][0], 0, 0, 0); \
    acc[3][1] = __builtin_amdgcn_mfma_f32_16x16x32_bf16(a3_, b1_, acc[3][1], 0, 0, 0); \
  }

      LD(ks, b0A, b1A, a0A, a1A, a2A, a3A);
      int j = ks;
      while (j + 2 <= ke - 1) {
        LD(j + 1, b0B, b1B, a0B, a1B, a2B, a3B);
        FMA(b0A, b1A, a0A, a1A, a2A, a3A);
        LD(j + 2, b0A, b1A, a0A, a1A, a2A, a3A);
        FMA(b0B, b1B, a0B, a1B, a2B, a3B);
        j += 2;
      }
      if (j < ke - 1) {
        LD(j + 1, b0B, b1B, a0B, a1B, a2B, a3B);
        FMA(b0A, b1A, a0A, a1A, a2A, a3A);
        FMA(b0B, b1B, a0B, a1B, a2B, a3B);
      } else {
        FMA(b0A, b1A, a0A, a1A, a2A, a3A);
      }
#undef LD
#undef FMA
    }
  } else {
    // f32 fallback (workspace too small): row-major x, convert inline
    const float* xrow = x + (size_t)(tokBase + row16) * IN_FEAT + kgrp * 8;
    #pragma unroll 2
    for (int j = ks; j < ke; ++j) {
      const int k = e0 + j;
      const int ib = (j < 64) ? __builtin_amdgcn_readlane(iiv, j) : ii[k];
      const float* wbp = w + (size_t)k * 1024 + kgrp * 8;
      const float4* wp0 = (const float4*)(wbp + row16 * 32);
      const float4* wp1 = (const float4*)(wbp + (row16 + 16) * 32);
      short8 b0 = cvt8(wp0[0], wp0[1]);
      short8 b1 = cvt8(wp1[0], wp1[1]);
      const float* xp = xrow + ib * 32;
      #pragma unroll
      for (int m = 0; m < 4; ++m) {
        const float4* ap = (const float4*)(xp + (size_t)(m * 16) * IN_FEAT);
        short8 a = cvt8(ap[0], ap[1]);
        acc[m][0] = __builtin_amdgcn_mfma_f32_16x16x32_bf16(a, b0, acc[m][0], 0, 0, 0);
        acc[m][1] = __builtin_amdgcn_mfma_f32_16x16x32_bf16(a, b1, acc[m][1], 0, 0, 0);
      }
    }
  }

  // tree reduce: (1->0, 3->2) then (2->0); wave 0 writes out.
  // acc[m][nf][r] -> LDS idx (m*16 + kgrp*4 + r)*32 + nf*16 + row16
  {
    float* b0p = red[0];
    float* b1p = red[1];
    if (wv == 1 || wv == 3) {
      float* b = (wv == 1) ? b0p : b1p;
      #pragma unroll
      for (int m = 0; m < 4; ++m)
        #pragma unroll
        for (int nf = 0; nf < 2; ++nf)
          #pragma unroll
          for (int r = 0; r < 4; ++r)
            b[(m * 16 + kgrp * 4 + r) * 32 + nf * 16 + row16] = acc[m][nf][r];
    }
    __syncthreads();
    if (wv == 0 || wv == 2) {
      const float* b = (wv == 0) ? b0p : b1p;
      #pragma unroll
      for (int m = 0; m < 4; ++m)
        #pragma unroll
        for (int nf = 0; nf < 2; ++nf)
          #pragma unroll
          for (int r = 0; r < 4; ++r)
            acc[m][nf][r] += b[(m * 16 + kgrp * 4 + r) * 32 + nf * 16 + row16];
    }
    __syncthreads();
    if (wv == 2) {
      #pragma unroll
      for (int m = 0; m < 4; ++m)
        #pragma unroll
        for (int nf = 0; nf < 2; ++nf)
          #pragma unroll
          for (int r = 0; r < 4; ++r)
            b0p[(m * 16 + kgrp * 4 + r) * 32 + nf * 16 + row16] = acc[m][nf][r];
    }
    __syncthreads();
    if (wv == 0) {
      #pragma unroll
      for (int m = 0; m < 4; ++m)
        #pragma unroll
        for (int nf = 0; nf < 2; ++nf)
          #pragma unroll
          for (int r = 0; r < 4; ++r) {
            float v = acc[m][nf][r] + b0p[(m * 16 + kgrp * 4 + r) * 32 + nf * 16 + row16];
            const int row = tokBase + m * 16 + kgrp * 4 + r;
            const int col = ob * 32 + nf * 16 + row16;
            y[(size_t)row * 2048 + col] = v;
          }
    }
  }
}

extern "C" void kernel_launch(void* const* d_in, const int* in_sizes, int n_in,
                              void* d_out, int out_size, void* d_ws, size_t ws_size,
                              hipStream_t stream) {
  const float* x  = (const float*)d_in[0];
  const float* w  = (const float*)d_in[1];
  const int*   oi = (const int*)d_in[2];
  const int*   ii = (const int*)d_in[3];
  float* y = (float*)d_out;

  const size_t need = (size_t)(XN8 + WN8) * 16 + 65 * sizeof(int);
  if (ws_size >= need) {
    short8* xb = (short8*)d_ws;
    short8* wb = xb + XN8;
    int* offs = (int*)(wb + WN8);
    cvt_kernel<<<dim3((XN8 + WN8 + 255) / 256), dim3(256), 0, stream>>>(x, w, oi, xb, wb, offs);
    bsl_main<1><<<dim3(2048), dim3(256), 0, stream>>>(xb, wb, offs, x, w, oi, ii, y);
  } else {
    bsl_main<0><<<dim3(2048), dim3(256), 0, stream>>>(nullptr, nullptr, nullptr, x, w, oi, ii, y);
  }
}